// Round 2
// baseline (256.088 us; speedup 1.0000x reference)
//
#include <hip/hip_runtime.h>

// Problem constants (from reference)
constexpr int Ni = 4, Ci = 256, Hi = 256, Wi = 256;
constexpr int Bn = 512, PHn = 7, PWn = 7, SRn = 2;
constexpr float SCALEf = 0.25f;

constexpr int NBINS = PHn * PWn;   // 49
constexpr int NSY = PHn * SRn;     // 14 y samples
constexpr int NSX = PWn * SRn;     // 14 x samples
constexpr int NROWS = 2 * NSY;     // 28 staged rows (ylo/yhi per sample)
constexpr int WSTG = 48;           // staged row width (covers 6.5*bin_w+2 <= 46.6)
constexpr int WPAD = 49;           // padded LDS stride (odd -> spreads banks)
constexpr int CCHUNK = 8;          // channels per block

__global__ __launch_bounds__(256) void roialign_kernel(
    const float* __restrict__ input,
    const float* __restrict__ rois,
    float* __restrict__ out)
{
    const int blk   = blockIdx.x;
    const int b     = blk / (Ci / CCHUNK);
    const int chunk = blk % (Ci / CCHUNK);

    __shared__ float s_patch[CCHUNK][NROWS][WPAD];
    __shared__ int   s_ylo[NSY], s_yhi[NSY], s_yv[NSY];
    __shared__ float s_lyf[NSY];
    __shared__ int   s_xlo[NSX], s_xhi[NSX], s_xv[NSX];
    __shared__ float s_lxf[NSX];
    __shared__ int   s_bidx;

    const int t = threadIdx.x;

    // ---- Phase A: per-ROI sample indices/weights (mirrors _interp_1d) ----
    if (t < NSY + NSX) {
        const float r0  = rois[b * 5 + 0];
        const float rx1 = rois[b * 5 + 1];
        const float ry1 = rois[b * 5 + 2];
        const float rx2 = rois[b * 5 + 3];
        const float ry2 = rois[b * 5 + 4];
        const float x1 = rx1 * SCALEf - 0.5f;
        const float y1 = ry1 * SCALEf - 0.5f;
        const float x2 = rx2 * SCALEf - 0.5f;
        const float y2 = ry2 * SCALEf - 0.5f;
        const float bin_w = (x2 - x1) / (float)PWn;
        const float bin_h = (y2 - y1) / (float)PHn;
        if (t == 0) s_bidx = (int)r0;

        const bool isY = (t < NSY);
        const int  s   = isY ? t : (t - NSY);
        const int  p   = s / SRn;
        const int  i   = s % SRn;
        const float off   = ((float)i + 0.5f) / (float)SRn;
        const float start = isY ? y1 : x1;
        const float binsz = isY ? bin_h : bin_w;
        const float c     = start + ((float)p + off) * binsz;
        const int   size  = isY ? Hi : Wi;

        const bool  valid = (c >= -1.0f) && (c <= (float)size);
        const float cc    = fmaxf(c, 0.0f);
        const float lo_f  = floorf(cc);
        int lo = min((int)lo_f, size - 1);
        int hi = min(lo + 1, size - 1);
        const float c_adj = (lo_f >= (float)(size - 1)) ? (float)(size - 1) : cc;
        const float frac  = c_adj - (float)lo;

        if (isY) { s_ylo[s] = lo; s_yhi[s] = hi; s_lyf[s] = frac; s_yv[s] = valid ? 1 : 0; }
        else     { s_xlo[s] = lo; s_xhi[s] = hi; s_lxf[s] = frac; s_xv[s] = valid ? 1 : 0; }
    }
    __syncthreads();

    const int bidx = s_bidx;
    const int x0   = s_xlo[0];   // min x (xs monotone nondecreasing)

    // ---- Phase B: coalesced row staging into LDS ----
    // Stage NROWS rows of WSTG contiguous floats per channel.
    constexpr int NCOPY = CCHUNK * NROWS * WSTG;   // 10752
    for (int idx = t; idx < NCOPY; idx += 256) {
        const int cl  = idx / (NROWS * WSTG);
        const int rem = idx % (NROWS * WSTG);
        const int r   = rem / WSTG;
        const int i   = rem % WSTG;
        const int s   = r >> 1;
        const int gy  = (r & 1) ? s_yhi[s] : s_ylo[s];
        const int gx  = min(x0 + i, Wi - 1);       // clamp: avoid OOB at buffer end
        const int c   = chunk * CCHUNK + cl;
        s_patch[cl][r][i] =
            input[(((size_t)bidx * Ci + c) * Hi + gy) * Wi + gx];
    }
    __syncthreads();

    // ---- Phase C: compute bins from LDS ----
    constexpr int NOUT = CCHUNK * NBINS;  // 392
    for (int o = t; o < NOUT; o += 256) {
        const int cl  = o / NBINS;
        const int bin = o % NBINS;
        const int ph  = bin / PWn;
        const int pw  = bin % PWn;

        float acc = 0.0f;
        #pragma unroll
        for (int iy = 0; iy < SRn; ++iy) {
            const int   sy  = ph * SRn + iy;
            const int   rlo = 2 * sy;
            const float ly  = s_lyf[sy];
            const float hy  = 1.0f - ly;
            const int   vy  = s_yv[sy];
            #pragma unroll
            for (int ix = 0; ix < SRn; ++ix) {
                const int   sx  = pw * SRn + ix;
                const int   dxl = s_xlo[sx] - x0;
                const int   dxh = s_xhi[sx] - x0;
                const float lx  = s_lxf[sx];
                const float hx  = 1.0f - lx;
                const float v11 = s_patch[cl][rlo    ][dxl];
                const float v12 = s_patch[cl][rlo    ][dxh];
                const float v21 = s_patch[cl][rlo + 1][dxl];
                const float v22 = s_patch[cl][rlo + 1][dxh];
                const float v   = hy * (hx * v11 + lx * v12) + ly * (hx * v21 + lx * v22);
                acc += (vy & s_xv[sx]) ? v : 0.0f;
            }
        }
        // coalesced store: o is contiguous within the block's output span
        out[((size_t)b * Ci + chunk * CCHUNK) * NBINS + o] = acc * (1.0f / (SRn * SRn));
    }
}

extern "C" void kernel_launch(void* const* d_in, const int* in_sizes, int n_in,
                              void* d_out, int out_size, void* d_ws, size_t ws_size,
                              hipStream_t stream) {
    const float* input = (const float*)d_in[0];
    const float* rois  = (const float*)d_in[1];
    float* out = (float*)d_out;

    const int grid = Bn * (Ci / CCHUNK);  // 512 * 32 = 16384 blocks
    roialign_kernel<<<grid, 256, 0, stream>>>(input, rois, out);
}

// Round 3
// 123.457 us; speedup vs baseline: 2.0743x; 2.0743x over previous
//
#include <hip/hip_runtime.h>

// Problem constants (from reference)
constexpr int Ni = 4, Ci = 256, Hi = 256, Wi = 256;
constexpr int Bn = 512, PHn = 7, PWn = 7, SRn = 2;
constexpr float SCALEf = 0.25f;

constexpr int NBINS = PHn * PWn;   // 49
constexpr int NSY = PHn * SRn;     // 14 y samples
constexpr int NSX = PWn * SRn;     // 14 x samples
constexpr int NROWS = 2 * NSY;     // 28 staged rows (ylo/yhi per sample)
constexpr int WSTG = 48;           // staged row width (covers 6.5*bin_w+2 <= 46.6)
constexpr int WPAD = 49;           // padded LDS stride (odd -> spreads banks)
constexpr int CCHUNK = 4;          // channels per block (22KB LDS -> 7 blocks/CU)
constexpr int NCHUNKS = Ci / CCHUNK;  // 64

__global__ __launch_bounds__(256) void roialign_kernel(
    const float* __restrict__ input,
    const float* __restrict__ rois,
    float* __restrict__ out)
{
    const int blk   = blockIdx.x;
    const int b     = blk >> 6;        // / NCHUNKS (64)
    const int chunk = blk & (NCHUNKS - 1);

    __shared__ float s_patch[CCHUNK][NROWS][WPAD];   // 21952 B
    __shared__ int   s_gy[NROWS];                    // merged ylo/yhi row table
    __shared__ float s_lyf[NSY];
    __shared__ int   s_yv[NSY];
    __shared__ int   s_xlo[NSX], s_xhi[NSX], s_xv[NSX];
    __shared__ float s_lxf[NSX];
    __shared__ int   s_bidx, s_x0;

    const int t = threadIdx.x;

    // ---- Phase A: per-ROI sample indices/weights (mirrors _interp_1d) ----
    if (t < NSY + NSX) {
        const float r0  = rois[b * 5 + 0];
        const float rx1 = rois[b * 5 + 1];
        const float ry1 = rois[b * 5 + 2];
        const float rx2 = rois[b * 5 + 3];
        const float ry2 = rois[b * 5 + 4];
        const float x1 = rx1 * SCALEf - 0.5f;
        const float y1 = ry1 * SCALEf - 0.5f;
        const float x2 = rx2 * SCALEf - 0.5f;
        const float y2 = ry2 * SCALEf - 0.5f;
        const float bin_w = (x2 - x1) / (float)PWn;
        const float bin_h = (y2 - y1) / (float)PHn;
        if (t == 0) s_bidx = (int)r0;

        const bool isY = (t < NSY);
        const int  s   = isY ? t : (t - NSY);
        const int  p   = s >> 1;            // / SRn
        const int  i   = s & 1;             // % SRn
        const float off   = ((float)i + 0.5f) / (float)SRn;
        const float start = isY ? y1 : x1;
        const float binsz = isY ? bin_h : bin_w;
        const float c     = start + ((float)p + off) * binsz;
        const int   size  = isY ? Hi : Wi;

        const bool  valid = (c >= -1.0f) && (c <= (float)size);
        const float cc    = fmaxf(c, 0.0f);
        const float lo_f  = floorf(cc);
        int lo = min((int)lo_f, size - 1);
        int hi = min(lo + 1, size - 1);
        const float c_adj = (lo_f >= (float)(size - 1)) ? (float)(size - 1) : cc;
        const float frac  = c_adj - (float)lo;

        if (isY) {
            s_gy[2 * s]     = lo;
            s_gy[2 * s + 1] = hi;
            s_lyf[s] = frac;
            s_yv[s]  = valid ? 1 : 0;
        } else {
            s_xlo[s] = lo; s_xhi[s] = hi; s_lxf[s] = frac; s_xv[s] = valid ? 1 : 0;
            if (s == 0) s_x0 = lo;   // xs monotone increasing -> xlo[0] is min
        }
    }
    __syncthreads();

    const int bidx = s_bidx;
    const int x0   = s_x0;

    // ---- Phase B: coalesced row staging, affine indexing (no div in loop) ----
    // threads 0..239: i = t%48 (column), rr = t/48 (row phase 0..4)
    {
        const int i  = t % WSTG;
        const int rr = t / WSTG;
        if (t < 240) {
            const int gxc = min(x0 + i, Wi - 1);     // hoisted clamp
            // hoist row table reads (reused across channels)
            int gy[6];
            #pragma unroll
            for (int k = 0; k < 6; ++k) {
                const int r = rr + 5 * k;
                gy[k] = (r < NROWS) ? s_gy[r] : 0;
            }
            const size_t base_b = (size_t)bidx * Ci * Hi * Wi;
            #pragma unroll
            for (int cl = 0; cl < CCHUNK; ++cl) {
                const float* plane = input + base_b
                    + (size_t)(chunk * CCHUNK + cl) * (Hi * Wi);
                #pragma unroll
                for (int k = 0; k < 6; ++k) {
                    const int r = rr + 5 * k;
                    if (r < NROWS) {
                        s_patch[cl][r][i] = plane[gy[k] * Wi + gxc];
                    }
                }
            }
        }
    }
    __syncthreads();

    // ---- Phase C: compute bins from LDS — single shot (196 <= 256 threads) ----
    if (t < CCHUNK * NBINS) {
        const int cl  = t / NBINS;          // one magic-div, once
        const int bin = t - cl * NBINS;
        const int ph  = bin / PWn;
        const int pw  = bin - ph * PWn;

        float acc = 0.0f;
        #pragma unroll
        for (int iy = 0; iy < SRn; ++iy) {
            const int   sy  = ph * SRn + iy;
            const int   rlo = 2 * sy;
            const float ly  = s_lyf[sy];
            const float hy  = 1.0f - ly;
            const int   vy  = s_yv[sy];
            #pragma unroll
            for (int ix = 0; ix < SRn; ++ix) {
                const int   sx  = pw * SRn + ix;
                const int   dxl = s_xlo[sx] - x0;
                const int   dxh = s_xhi[sx] - x0;
                const float lx  = s_lxf[sx];
                const float hx  = 1.0f - lx;
                const float v11 = s_patch[cl][rlo    ][dxl];
                const float v12 = s_patch[cl][rlo    ][dxh];
                const float v21 = s_patch[cl][rlo + 1][dxl];
                const float v22 = s_patch[cl][rlo + 1][dxh];
                const float v   = hy * (hx * v11 + lx * v12) + ly * (hx * v21 + lx * v22);
                acc += (vy & s_xv[sx]) ? v : 0.0f;
            }
        }
        out[((size_t)b * Ci + chunk * CCHUNK) * NBINS + t] = acc * (1.0f / (SRn * SRn));
    }
}

extern "C" void kernel_launch(void* const* d_in, const int* in_sizes, int n_in,
                              void* d_out, int out_size, void* d_ws, size_t ws_size,
                              hipStream_t stream) {
    const float* input = (const float*)d_in[0];
    const float* rois  = (const float*)d_in[1];
    float* out = (float*)d_out;

    const int grid = Bn * NCHUNKS;  // 512 * 64 = 32768 blocks
    roialign_kernel<<<grid, 256, 0, stream>>>(input, rois, out);
}

// Round 4
// 98.493 us; speedup vs baseline: 2.6001x; 1.2535x over previous
//
#include <hip/hip_runtime.h>

// Problem constants (from reference)
constexpr int Ni = 4, Ci = 256, Hi = 256, Wi = 256;
constexpr int Bn = 512, PHn = 7, PWn = 7, SRn = 2;
constexpr float SCALEf = 0.25f;

constexpr int NBINS = PHn * PWn;   // 49
constexpr int NSY = PHn * SRn;     // 14 y samples
constexpr int NSX = PWn * SRn;     // 14 x samples
constexpr int NROWS = 2 * NSY;     // 28 staged rows (ylo/yhi per sample)
constexpr int WSTG = 48;           // max staged row width (6.5*bin_w+2 <= 47)
constexpr int WPAD = 49;           // padded LDS stride (odd -> spreads banks)
constexpr int CCHUNK = 4;          // channels per block (22KB LDS)
constexpr int NCHUNKS = Ci / CCHUNK;  // 64

__global__ __launch_bounds__(256) void roialign_kernel(
    const float* __restrict__ input,
    const float* __restrict__ rois,
    float* __restrict__ out)
{
    // ---- chunk-major + XCD-aware decomposition ----
    // xcd = blk % 8 (HW round-robin); each XCD walks 8 consecutive
    // 4-channel slabs (4 img x 4 ch x 256KB = 4MB = one XCD L2) over all ROIs.
    const int blk   = blockIdx.x;
    const int xcd   = blk & 7;
    const int idx   = blk >> 3;            // 0..4095
    const int chunk = xcd * 8 + (idx >> 9);  // 0..63
    const int b     = idx & 511;             // ROI id

    __shared__ float s_patch[CCHUNK][NROWS][WPAD];   // 21952 B
    __shared__ int   s_gy[NROWS];                    // merged ylo/yhi row table
    __shared__ float s_lyf[NSY];
    __shared__ int   s_yv[NSY];
    __shared__ int   s_xlo[NSX], s_xhi[NSX], s_xv[NSX];
    __shared__ float s_lxf[NSX];
    __shared__ int   s_bidx, s_x0, s_xspan;

    const int t = threadIdx.x;

    // ---- Phase A: per-ROI sample indices/weights (mirrors _interp_1d) ----
    if (t < NSY + NSX) {
        const float r0  = rois[b * 5 + 0];
        const float rx1 = rois[b * 5 + 1];
        const float ry1 = rois[b * 5 + 2];
        const float rx2 = rois[b * 5 + 3];
        const float ry2 = rois[b * 5 + 4];
        const float x1 = rx1 * SCALEf - 0.5f;
        const float y1 = ry1 * SCALEf - 0.5f;
        const float x2 = rx2 * SCALEf - 0.5f;
        const float y2 = ry2 * SCALEf - 0.5f;
        const float bin_w = (x2 - x1) / (float)PWn;
        const float bin_h = (y2 - y1) / (float)PHn;
        if (t == 0) s_bidx = (int)r0;

        const bool isY = (t < NSY);
        const int  s   = isY ? t : (t - NSY);
        const int  p   = s >> 1;            // / SRn
        const int  i   = s & 1;             // % SRn
        const float off   = ((float)i + 0.5f) / (float)SRn;
        const float start = isY ? y1 : x1;
        const float binsz = isY ? bin_h : bin_w;
        const float c     = start + ((float)p + off) * binsz;
        const int   size  = isY ? Hi : Wi;

        const bool  valid = (c >= -1.0f) && (c <= (float)size);
        const float cc    = fmaxf(c, 0.0f);
        const float lo_f  = floorf(cc);
        int lo = min((int)lo_f, size - 1);
        int hi = min(lo + 1, size - 1);
        const float c_adj = (lo_f >= (float)(size - 1)) ? (float)(size - 1) : cc;
        const float frac  = c_adj - (float)lo;

        if (isY) {
            s_gy[2 * s]     = lo;
            s_gy[2 * s + 1] = hi;
            s_lyf[s] = frac;
            s_yv[s]  = valid ? 1 : 0;
        } else {
            s_xlo[s] = lo; s_xhi[s] = hi; s_lxf[s] = frac; s_xv[s] = valid ? 1 : 0;
            if (s == 0) s_x0 = lo;                   // xs monotone -> min
            if (s == NSX - 1) s_xspan = 0;           // placeholder, fixed below
        }
    }
    __syncthreads();
    if (t == 0) s_xspan = s_xhi[NSX - 1] - s_x0 + 1;  // exact staged width
    __syncthreads();

    const int bidx  = s_bidx;
    const int x0    = s_x0;
    const int xspan = s_xspan;   // <= 48

    // ---- Phase B: coalesced row staging, exact width, affine indexing ----
    // threads 0..239: i = t%48 (column), rr = t/48 (row phase 0..4)
    {
        const int i  = t % WSTG;
        const int rr = t / WSTG;
        if (t < 240 && i < xspan) {
            const int gxc = min(x0 + i, Wi - 1);
            int gy[6];
            #pragma unroll
            for (int k = 0; k < 6; ++k) {
                const int r = rr + 5 * k;
                gy[k] = (r < NROWS) ? s_gy[r] : 0;
            }
            const size_t base_b = (size_t)bidx * Ci * Hi * Wi;
            #pragma unroll
            for (int cl = 0; cl < CCHUNK; ++cl) {
                const float* plane = input + base_b
                    + (size_t)(chunk * CCHUNK + cl) * (Hi * Wi);
                #pragma unroll
                for (int k = 0; k < 6; ++k) {
                    const int r = rr + 5 * k;
                    if (r < NROWS) {
                        s_patch[cl][r][i] = plane[gy[k] * Wi + gxc];
                    }
                }
            }
        }
    }
    __syncthreads();

    // ---- Phase C: compute bins from LDS — single shot (196 <= 256 threads) ----
    if (t < CCHUNK * NBINS) {
        const int cl  = t / NBINS;
        const int bin = t - cl * NBINS;
        const int ph  = bin / PWn;
        const int pw  = bin - ph * PWn;

        float acc = 0.0f;
        #pragma unroll
        for (int iy = 0; iy < SRn; ++iy) {
            const int   sy  = ph * SRn + iy;
            const int   rlo = 2 * sy;
            const float ly  = s_lyf[sy];
            const float hy  = 1.0f - ly;
            const int   vy  = s_yv[sy];
            #pragma unroll
            for (int ix = 0; ix < SRn; ++ix) {
                const int   sx  = pw * SRn + ix;
                const int   dxl = s_xlo[sx] - x0;
                const int   dxh = s_xhi[sx] - x0;
                const float lx  = s_lxf[sx];
                const float hx  = 1.0f - lx;
                const float v11 = s_patch[cl][rlo    ][dxl];
                const float v12 = s_patch[cl][rlo    ][dxh];
                const float v21 = s_patch[cl][rlo + 1][dxl];
                const float v22 = s_patch[cl][rlo + 1][dxh];
                const float v   = hy * (hx * v11 + lx * v12) + ly * (hx * v21 + lx * v22);
                acc += (vy & s_xv[sx]) ? v : 0.0f;
            }
        }
        out[((size_t)b * Ci + chunk * CCHUNK) * NBINS + t] = acc * (1.0f / (SRn * SRn));
    }
}

extern "C" void kernel_launch(void* const* d_in, const int* in_sizes, int n_in,
                              void* d_out, int out_size, void* d_ws, size_t ws_size,
                              hipStream_t stream) {
    const float* input = (const float*)d_in[0];
    const float* rois  = (const float*)d_in[1];
    float* out = (float*)d_out;

    const int grid = Bn * NCHUNKS;  // 512 * 64 = 32768 blocks
    roialign_kernel<<<grid, 256, 0, stream>>>(input, rois, out);
}